// Round 3
// baseline (13022.357 us; speedup 1.0000x reference)
//
#include <hip/hip_runtime.h>
#include <hip/hip_cooperative_groups.h>

#define NB 32
#define NT 1024
#define NH 512
#define NE 256
#define NV0 2048
#define NV1 512
#define G3H 1536

typedef __attribute__((ext_vector_type(8))) short bf16x8;
typedef __attribute__((ext_vector_type(4))) float f32x4;
typedef unsigned short u16;

__device__ __forceinline__ u16 bf16_hi(float x) {
  unsigned u = __float_as_uint(x);
  unsigned r = (u + 0x7FFF + ((u >> 16) & 1)) >> 16;
  return (u16)r;
}
__device__ __forceinline__ float bf16_f(u16 h) {
  return __uint_as_float(((unsigned)h) << 16);
}

// ---------------- prep ----------------

__global__ void k_init(const float* __restrict__ hidden, u16* __restrict__ bufh,
                       u16* __restrict__ bufl) {
  int i = blockIdx.x * blockDim.x + threadIdx.x;
  if (i < NB * NH) {
    float v = hidden[i];
    u16 hi = bf16_hi(v);
    bufh[i] = hi;
    bufl[i] = bf16_hi(v - bf16_f(hi));
  }
}

__global__ void k_transpose(const float* __restrict__ in, float* __restrict__ out) {
  __shared__ float tile[32][33];
  int bx = blockIdx.x, by = blockIdx.y;
  int x = threadIdx.x, y = threadIdx.y;
  #pragma unroll
  for (int j = 0; j < 4; ++j)
    tile[y + j * 8][x] = in[(by * 32 + y + j * 8) * 512 + bx * 32 + x];
  __syncthreads();
  #pragma unroll
  for (int j = 0; j < 4; ++j)
    out[(bx * 32 + y + j * 8) * 1536 + by * 32 + x] = tile[x][y + j * 8];
}

__global__ __launch_bounds__(256) void k_proj(const float* __restrict__ emb0,
                                              const float* __restrict__ emb1,
                                              const float* __restrict__ Wt_ih,
                                              float* __restrict__ proj0,
                                              float* __restrict__ proj1) {
  __shared__ float a[8][NE];
  int g0 = blockIdx.x * 8;
  int tid = threadIdx.x;
  for (int i = tid; i < 8 * NE; i += 256) {
    int v = g0 + (i >> 8);
    int k = i & 255;
    a[i >> 8][k] = (v < NV0) ? emb0[v * NE + k] : emb1[(v - NV0) * NE + k];
  }
  __syncthreads();
  bool is0 = (g0 < NV0);
  int koff = is0 ? 0 : NE;
  float acc[8][6];
  #pragma unroll
  for (int v = 0; v < 8; ++v)
    #pragma unroll
    for (int j = 0; j < 6; ++j) acc[v][j] = 0.f;
  for (int k = 0; k < NE; ++k) {
    const float* wrow = Wt_ih + (size_t)(k + koff) * G3H;
    float w[6];
    #pragma unroll
    for (int j = 0; j < 6; ++j) w[j] = wrow[tid + j * 256];
    #pragma unroll
    for (int v = 0; v < 8; ++v) {
      float av = a[v][k];
      #pragma unroll
      for (int j = 0; j < 6; ++j) acc[v][j] += av * w[j];
    }
  }
  float* outp = is0 ? (proj0 + (size_t)g0 * G3H) : (proj1 + (size_t)(g0 - NV0) * G3H);
  for (int v = 0; v < 8; ++v)
    for (int j = 0; j < 6; ++j)
      outp[(size_t)v * G3H + tid + j * 256] = acc[v][j];
}

// W_hh split (rnn layout): itemrow=(hh>>5)*96+g*32+(hh&31)
__global__ void k_wsplit(const float* __restrict__ W_hh, u16* __restrict__ Wfh,
                         u16* __restrict__ Wfl) {
  int idx = blockIdx.x * blockDim.x + threadIdx.x;
  if (idx >= G3H * NH) return;
  int row = idx >> 9, k = idx & 511;
  int g = row >> 9, hh = row & 511;
  int itemrow = (hh >> 5) * 96 + g * 32 + (hh & 31);
  size_t phys = ((size_t)((itemrow >> 4) * 64 + (k >> 3))) * 128 + (itemrow & 15) * 8 + (k & 7);
  float v = W_hh[idx];
  u16 hi = bf16_hi(v);
  Wfh[phys] = hi;
  Wfl[phys] = bf16_hi(v - bf16_f(hi));
}

// dec weights split, plain tile-major frag layout
__global__ void k_wsplit_dec(const float* __restrict__ W, u16* __restrict__ Wh,
                             u16* __restrict__ Wl, int R) {
  int idx = blockIdx.x * blockDim.x + threadIdx.x;
  if (idx >= R * 512) return;
  int row = idx >> 9, k = idx & 511;
  size_t phys = ((size_t)(row >> 4) * 64 + (k >> 3)) * 128 + (row & 15) * 8 + (k & 7);
  float v = W[idx];
  u16 hi = bf16_hi(v);
  Wh[phys] = hi;
  Wl[phys] = bf16_hi(v - bf16_f(hi));
}

__global__ void k_levels(const int* __restrict__ cond, int* __restrict__ plv,
                         int* __restrict__ cntb) {
  __shared__ int c_lds[NT];
  __shared__ int lvl[NT + 1];
  __shared__ int cnt[NT + 1];
  int b = blockIdx.x, tid = threadIdx.x;
  for (int i = tid; i < NT; i += 256) c_lds[i] = cond[b * NT + i];
  for (int i = tid; i <= NT; i += 256) cnt[i] = 0;
  __syncthreads();
  if (tid == 0) {
    lvl[0] = 0;
    for (int t = 0; t < NT; ++t) {
      lvl[t + 1] = lvl[c_lds[t]] + 1;
      cnt[lvl[t + 1] - 1]++;
    }
  }
  __syncthreads();
  for (int t = tid; t < NT; t += 256) plv[b * NT + t] = lvl[t + 1] - 1;
  for (int p = tid; p <= NT; p += 256) cntb[p * NB + b] = cnt[p];
}

__global__ void k_scan(const int* __restrict__ cntb, int* __restrict__ level_offset,
                       int* __restrict__ startpb, int* __restrict__ level_n,
                       int* __restrict__ meta) {
  __shared__ int rowsum[NT + 1];
  int tid = threadIdx.x;
  for (int p = tid; p <= NT; p += 1024) {
    int s = 0;
    for (int b = 0; b < NB; ++b) s += cntb[p * NB + b];
    rowsum[p] = s;
    level_n[p] = s;
  }
  __syncthreads();
  if (tid == 0) {
    int off = 0, Lmax = 0;
    for (int p = 0; p <= NT; ++p) {
      level_offset[p] = off;
      if (rowsum[p] > 0) Lmax = p + 1;
      off += rowsum[p];
    }
    meta[0] = Lmax;
    meta[1] = 0;  // barrier count
    meta[2] = 0;  // barrier generation
  }
  __syncthreads();
  for (int p = tid; p <= NT; p += 1024) {
    int off = level_offset[p];
    for (int b = 0; b < NB; ++b) {
      startpb[p * NB + b] = off;
      off += cntb[p * NB + b];
    }
  }
}

__global__ void k_scatter(const int* __restrict__ plv, const int* __restrict__ startpb,
                          int* __restrict__ node_list) {
  __shared__ int cur[NT + 1];
  int b = blockIdx.x, tid = threadIdx.x;
  for (int p = tid; p <= NT; p += 256) cur[p] = startpb[p * NB + b];
  __syncthreads();
  if (tid == 0) {
    for (int t = 0; t < NT; ++t) {
      int p = plv[b * NT + t];
      node_list[cur[p]++] = (b << 16) | t;
    }
  }
}

// ---------------- custom grid barrier (ockl-equivalent, cheaper at 256 WGs) ----------------

__device__ __forceinline__ void grid_bar(int* cnt, int* gen, int nwg, int p) {
  __syncthreads();
  if (threadIdx.x == 0) {
    __threadfence();  // agent-scope release (L2 writeback)
    int old = __hip_atomic_fetch_add(cnt, 1, __ATOMIC_ACQ_REL, __HIP_MEMORY_SCOPE_AGENT);
    if (old == nwg - 1) {
      __hip_atomic_store(cnt, 0, __ATOMIC_RELAXED, __HIP_MEMORY_SCOPE_AGENT);
      __hip_atomic_store(gen, p + 1, __ATOMIC_RELEASE, __HIP_MEMORY_SCOPE_AGENT);
    } else {
      while (__hip_atomic_load(gen, __ATOMIC_ACQUIRE, __HIP_MEMORY_SCOPE_AGENT) <= p)
        __builtin_amdgcn_s_sleep(8);
    }
    __threadfence();  // agent-scope acquire (invalidate stale lines)
  }
  __syncthreads();
}

// ---------------- recurrence: level-parallel, in-register GRU ----------------

__global__ __launch_bounds__(512, 2) void rnn_steps(
    const int* __restrict__ node_list, const int* __restrict__ level_n,
    const int* __restrict__ level_offset, const int* __restrict__ meta,
    const int* __restrict__ cond, const int* __restrict__ tok0, const int* __restrict__ tok1,
    const u16* __restrict__ Wfh, const u16* __restrict__ Wfl,
    const float* __restrict__ proj0, const float* __restrict__ proj1,
    const float* __restrict__ b_ih, const float* __restrict__ b_hh,
    u16* __restrict__ bufh, u16* __restrict__ bufl,
    int* __restrict__ bar_cnt, int* __restrict__ bar_gen, int nwg) {
  __shared__ unsigned char hds_h[16 * 1024];
  __shared__ unsigned char hds_l[16 * 1024];
  __shared__ int s_tb[16], s_par[16], s_k0[16], s_k1[16];
  int tid = threadIdx.x;
  int v = tid >> 6, lane = tid & 63, q = lane >> 4, m = lane & 15;
  int L = meta[0];
  for (int p = 0; p < L; ++p) {
    int n = level_n[p];
    int base = level_offset[p];
    int items = ((n + 15) >> 4) << 2;  // node-groups * 4 hh-chunks
    for (int it = blockIdx.x; it < items; it += gridDim.x) {
      int grp = it >> 2, c = it & 3;
      int nb = n - grp * 16; if (nb > 16) nb = 16;
      __syncthreads();  // protect LDS across items
      if (tid < 16) {
        int b = 0, t = -1, par = 0, q0 = 0, q1 = 0;
        if (tid < nb) {
          int pk = node_list[base + grp * 16 + tid];
          b = pk >> 16; t = pk & 0xFFFF;
          par = cond[b * NT + t];
          q0 = tok0[b * NT + t];
          q1 = tok1[b * NT + t];
        }
        s_tb[tid] = (t + 1) * NB + b;
        s_par[tid] = par * NB + b;
        s_k0[tid] = q0; s_k1[tid] = q1;
      }
      __syncthreads();
      // stage parent h (hi/lo) into LDS, swizzled 16B slots: 2048 uint4 / 512 thr
      #pragma unroll
      for (int r = 0; r < 4; ++r) {
        int idx = r * 512 + tid;
        int arr = idx >> 10, rem = idx & 1023;
        int row = rem >> 6, cc = rem & 63;
        const u16* srcb = arr ? bufl : bufh;
        uint4 val = *(const uint4*)(srcb + (size_t)s_par[row] * NH + cc * 8);
        unsigned char* dstb = arr ? hds_l : hds_h;
        *(uint4*)(dstb + row * 1024 + ((cc * 16) ^ ((row & 7) << 4))) = val;
      }
      __syncthreads();
      // MFMA: wave v owns hh-16-block hb = c*8+v, gates 0..2; 16 nodes
      int hb = c * 8 + v;
      int trbase = (hb >> 1) * 6 + (hb & 1);
      f32x4 a0 = {0.f, 0.f, 0.f, 0.f}, a1 = {0.f, 0.f, 0.f, 0.f}, a2 = {0.f, 0.f, 0.f, 0.f};
      const u16* wh = Wfh + (size_t)trbase * 8192;
      const u16* wl = Wfl + (size_t)trbase * 8192;
      #pragma unroll 4
      for (int s = 0; s < 16; ++s) {
        int ab = m * 1024 + (((s * 64) + (q * 16)) ^ ((m & 7) << 4));
        bf16x8 ah = *(const bf16x8*)(hds_h + ab);
        bf16x8 al = *(const bf16x8*)(hds_l + ab);
        size_t koff = (size_t)(s * 4 + q) * 128 + m * 8;
        bf16x8 bh0 = *(const bf16x8*)(wh + koff);
        bf16x8 bl0 = *(const bf16x8*)(wl + koff);
        bf16x8 bh1 = *(const bf16x8*)(wh + 16384 + koff);
        bf16x8 bl1 = *(const bf16x8*)(wl + 16384 + koff);
        bf16x8 bh2 = *(const bf16x8*)(wh + 32768 + koff);
        bf16x8 bl2 = *(const bf16x8*)(wl + 32768 + koff);
        a0 = __builtin_amdgcn_mfma_f32_16x16x32_bf16(ah, bh0, a0, 0, 0, 0);
        a0 = __builtin_amdgcn_mfma_f32_16x16x32_bf16(ah, bl0, a0, 0, 0, 0);
        a0 = __builtin_amdgcn_mfma_f32_16x16x32_bf16(al, bh0, a0, 0, 0, 0);
        a1 = __builtin_amdgcn_mfma_f32_16x16x32_bf16(ah, bh1, a1, 0, 0, 0);
        a1 = __builtin_amdgcn_mfma_f32_16x16x32_bf16(ah, bl1, a1, 0, 0, 0);
        a1 = __builtin_amdgcn_mfma_f32_16x16x32_bf16(al, bh1, a1, 0, 0, 0);
        a2 = __builtin_amdgcn_mfma_f32_16x16x32_bf16(ah, bh2, a2, 0, 0, 0);
        a2 = __builtin_amdgcn_mfma_f32_16x16x32_bf16(ah, bl2, a2, 0, 0, 0);
        a2 = __builtin_amdgcn_mfma_f32_16x16x32_bf16(al, bh2, a2, 0, 0, 0);
      }
      // in-register nonlinearity: lane (q,m) holds gates r,z,n for node q*4+i, hh=hb*16+m
      int hh = hb * 16 + m;
      float bi_r = b_ih[hh] + b_hh[hh];
      float bi_z = b_ih[NH + hh] + b_hh[NH + hh];
      float bi_n = b_ih[2 * NH + hh];
      float bh_n = b_hh[2 * NH + hh];
      #pragma unroll
      for (int i = 0; i < 4; ++i) {
        int node = q * 4 + i;
        if (node < nb) {
          const float* p0 = proj0 + (size_t)s_k0[node] * G3H;
          const float* p1 = proj1 + (size_t)s_k1[node] * G3H;
          float gr = a0[i] + p0[hh] + p1[hh] + bi_r;
          float gz = a1[i] + p0[NH + hh] + p1[NH + hh] + bi_z;
          float gin = p0[2 * NH + hh] + p1[2 * NH + hh] + bi_n;
          float ghn = a2[i] + bh_n;
          float rg = 1.f / (1.f + __expf(-gr));
          float zg = 1.f / (1.f + __expf(-gz));
          float nn = 1.f - 2.f / (1.f + __expf(2.f * (gin + rg * ghn)));
          int hofs = node * 1024 + ((hh * 2) ^ ((node & 7) << 4));
          float hp = bf16_f(*(const u16*)(hds_h + hofs)) + bf16_f(*(const u16*)(hds_l + hofs));
          float hn = (1.f - zg) * nn + zg * hp;
          u16 hi = bf16_hi(hn);
          size_t o = (size_t)s_tb[node] * NH + hh;
          bufh[o] = hi;
          bufl[o] = bf16_hi(hn - bf16_f(hi));
        }
      }
    }
    grid_bar(bar_cnt, bar_gen, nwg, p);
  }
}

// ---------------- decode GEMM: MFMA bf16 3-split ----------------

__global__ __launch_bounds__(256) void k_dec(const u16* __restrict__ bufh,
                                             const u16* __restrict__ bufl,
                                             const u16* __restrict__ Wh,
                                             const u16* __restrict__ Wl,
                                             const float* __restrict__ bias,
                                             float* __restrict__ out, int N) {
  __shared__ u16 Ah[64 * 128];
  __shared__ u16 Al[64 * 128];
  int tid = threadIdx.x;
  int w = tid >> 6, lane = tid & 63, q = lane >> 4, m = lane & 15;
  int n0 = blockIdx.x * 64, m0 = blockIdx.y * 64;
  f32x4 acc[4];
  #pragma unroll
  for (int n = 0; n < 4; ++n) acc[n] = (f32x4){0.f, 0.f, 0.f, 0.f};
  for (int c = 0; c < 4; ++c) {
    __syncthreads();
    #pragma unroll
    for (int r = 0; r < 8; ++r) {
      int idx = r * 256 + tid;
      int arr = idx >> 10, rem = idx & 1023;
      int row = rem >> 4, seg = rem & 15;
      int gm = m0 + row;
      size_t bufrow = (size_t)((gm & (NT - 1)) + 1) * NB + (gm >> 10);
      const u16* srcb = arr ? bufl : bufh;
      uint4 val = *(const uint4*)(srcb + bufrow * NH + c * 128 + seg * 8);
      u16* dstb = arr ? Al : Ah;
      *(uint4*)((unsigned char*)dstb + row * 256 + ((seg * 16) ^ ((row & 7) << 4))) = val;
    }
    __syncthreads();
    #pragma unroll
    for (int s = 0; s < 4; ++s) {
      int arow = w * 16 + m;
      int aoff = arow * 256 + (((s * 64) + (q * 16)) ^ ((arow & 7) << 4));
      bf16x8 ah = *(const bf16x8*)((unsigned char*)Ah + aoff);
      bf16x8 al = *(const bf16x8*)((unsigned char*)Al + aoff);
      #pragma unroll
      for (int n = 0; n < 4; ++n) {
        size_t b = ((size_t)(n0 / 16 + n) * 64 + (c * 16 + s * 4 + q)) * 128 + m * 8;
        bf16x8 bh = *(const bf16x8*)(Wh + b);
        bf16x8 bl = *(const bf16x8*)(Wl + b);
        acc[n] = __builtin_amdgcn_mfma_f32_16x16x32_bf16(ah, bh, acc[n], 0, 0, 0);
        acc[n] = __builtin_amdgcn_mfma_f32_16x16x32_bf16(ah, bl, acc[n], 0, 0, 0);
        acc[n] = __builtin_amdgcn_mfma_f32_16x16x32_bf16(al, bh, acc[n], 0, 0, 0);
      }
    }
  }
  #pragma unroll
  for (int n = 0; n < 4; ++n) {
    int col = n0 + n * 16 + m;
    float bv = bias[col];
    #pragma unroll
    for (int i = 0; i < 4; ++i) {
      int mrow = m0 + w * 16 + q * 4 + i;
      out[(size_t)mrow * N + col] = acc[n][i] + bv;
    }
  }
}

__global__ void k_tail(const u16* __restrict__ bufh, const u16* __restrict__ bufl,
                       float* __restrict__ out) {
  int i = blockIdx.x * blockDim.x + threadIdx.x;
  if (i < NB * NH) {
    size_t idx = (size_t)NT * NB * NH + i;
    out[i] = bf16_f(bufh[idx]) + bf16_f(bufl[idx]);
  }
}

// ---------------- launch ----------------

extern "C" void kernel_launch(void* const* d_in, const int* in_sizes, int n_in,
                              void* d_out, int out_size, void* d_ws, size_t ws_size,
                              hipStream_t stream) {
  const int*   tokens0    = (const int*)d_in[0];
  const int*   tokens1    = (const int*)d_in[1];
  const int*   conditions = (const int*)d_in[2];
  const float* hidden     = (const float*)d_in[3];
  const float* emb0       = (const float*)d_in[4];
  const float* emb1       = (const float*)d_in[5];
  const float* W_ih       = (const float*)d_in[6];
  const float* W_hh       = (const float*)d_in[7];
  const float* b_ih       = (const float*)d_in[8];
  const float* b_hh       = (const float*)d_in[9];
  const float* dec0_W     = (const float*)d_in[10];
  const float* dec0_b     = (const float*)d_in[11];
  const float* dec1_W     = (const float*)d_in[12];
  const float* dec1_b     = (const float*)d_in[13];

  char* wsb = (char*)d_ws;
  float* proj0 = (float*)wsb;                      // 12,582,912 B
  float* proj1 = (float*)(wsb + 12582912);         //  3,145,728 B
  float* Wt_ih = (float*)(wsb + 15728640);         //  3,145,728 B
  u16*   bufh  = (u16*)(wsb + 18874368);           // 33,587,200 B
  u16*   bufl  = (u16*)(wsb + 52461568);           // 33,587,200 B
  u16*   Wfh   = (u16*)(wsb + 86048768);           //  1,572,864 B
  u16*   Wfl   = (u16*)(wsb + 87621632);           //  1,572,864 B
  u16*   d0Wh  = (u16*)(wsb + 89194496);           //  2,097,152 B
  u16*   d0Wl  = (u16*)(wsb + 91291648);           //  2,097,152 B
  u16*   d1Wh  = (u16*)(wsb + 93388800);           //    524,288 B
  u16*   d1Wl  = (u16*)(wsb + 93913088);           //    524,288 B
  int*   iws   = (int*)(wsb + 94437376);
  int* plv          = iws;                 // 32768
  int* cntb         = iws + 32768;         // 32800
  int* level_offset = iws + 65568;         // 1026
  int* startpb      = iws + 66594;         // 32800
  int* level_n      = iws + 99394;         // 1025
  int* meta         = iws + 100419;        // 8  ([0]=L, [1]=bar_cnt, [2]=bar_gen)
  int* node_list    = iws + 100427;        // 32768

  float* out0 = (float*)d_out;
  float* out1 = out0 + (size_t)NB * NT * NV0;
  float* outT = out1 + (size_t)NB * NT * NV1;

  k_init<<<64, 256, 0, stream>>>(hidden, bufh, bufl);
  k_transpose<<<dim3(16, 48), dim3(32, 8), 0, stream>>>(W_ih, Wt_ih);
  k_proj<<<320, 256, 0, stream>>>(emb0, emb1, Wt_ih, proj0, proj1);
  k_wsplit<<<3072, 256, 0, stream>>>(W_hh, Wfh, Wfl);
  k_wsplit_dec<<<4096, 256, 0, stream>>>(dec0_W, d0Wh, d0Wl, NV0);
  k_wsplit_dec<<<1024, 256, 0, stream>>>(dec1_W, d1Wh, d1Wl, NV1);
  k_levels<<<32, 256, 0, stream>>>(conditions, plv, cntb);
  k_scan<<<1, 1024, 0, stream>>>(cntb, level_offset, startpb, level_n, meta);
  k_scatter<<<32, 256, 0, stream>>>(plv, startpb, node_list);

  int maxb = 0;
  if (hipOccupancyMaxActiveBlocksPerMultiprocessor(&maxb, (const void*)rnn_steps, 512, 0) !=
          hipSuccess || maxb < 1)
    maxb = 1;
  int nwg = maxb * 256;
  if (nwg > 256) nwg = 256;
  {
    const int* a0 = node_list; const int* a1 = level_n; const int* a2 = level_offset;
    const int* a3 = meta; const int* a4 = conditions; const int* a5 = tokens0;
    const int* a6 = tokens1;
    const u16* a7 = Wfh; const u16* a8 = Wfl;
    const float* a9 = proj0; const float* a10 = proj1;
    const float* a11 = b_ih; const float* a12 = b_hh;
    u16* a13 = bufh; u16* a14 = bufl;
    int* a15 = meta + 1; int* a16 = meta + 2; int a17 = nwg;
    void* kargs[] = { &a0, &a1, &a2, &a3, &a4, &a5, &a6, &a7, &a8, &a9, &a10,
                      &a11, &a12, &a13, &a14, &a15, &a16, &a17 };
    hipLaunchCooperativeKernel((const void*)rnn_steps, dim3(nwg), dim3(512), kargs, 0, stream);
  }

  k_dec<<<dim3(NV0 / 64, (NB * NT) / 64), 256, 0, stream>>>(bufh, bufl, d0Wh, d0Wl, dec0_b, out0, NV0);
  k_dec<<<dim3(NV1 / 64, (NB * NT) / 64), 256, 0, stream>>>(bufh, bufl, d1Wh, d1Wl, dec1_b, out1, NV1);
  k_tail<<<64, 256, 0, stream>>>(bufh, bufl, outT);
}

// Round 4
// 3490.774 us; speedup vs baseline: 3.7305x; 3.7305x over previous
//
#include <hip/hip_runtime.h>

#define NB 32
#define NT 1024
#define NH 512
#define NE 256
#define NV0 2048
#define NV1 512
#define G3H 1536

typedef __attribute__((ext_vector_type(8))) short bf16x8;
typedef __attribute__((ext_vector_type(4))) float f32x4;
typedef unsigned short u16;
typedef unsigned int u32;

__device__ __forceinline__ u16 bf16_hi(float x) {
  unsigned u = __float_as_uint(x);
  unsigned r = (u + 0x7FFF + ((u >> 16) & 1)) >> 16;
  return (u16)r;
}
__device__ __forceinline__ float bf16_f(u16 h) {
  return __uint_as_float(((unsigned)h) << 16);
}
__device__ __forceinline__ u32 pack_hl(float v) {
  u16 hi = bf16_hi(v);
  u16 lo = bf16_hi(v - bf16_f(hi));
  return (u32)hi | ((u32)lo << 16);
}
__device__ __forceinline__ float unpack_hl(u32 w) {
  return bf16_f((u16)w) + bf16_f((u16)(w >> 16));
}

// ---------------- prep ----------------

// bufp row 0 from hidden; done flags: row-0 states preset done(=4), rest 0
__global__ void k_init(const float* __restrict__ hidden, u32* __restrict__ bufp,
                       int* __restrict__ done) {
  int i = blockIdx.x * blockDim.x + threadIdx.x;
  if (i < NB * NH) bufp[i] = pack_hl(hidden[i]);
  if (i < (NT + 1) * NB) done[i] = (i < NB) ? 4 : 0;
}

__global__ void k_transpose(const float* __restrict__ in, float* __restrict__ out) {
  __shared__ float tile[32][33];
  int bx = blockIdx.x, by = blockIdx.y;
  int x = threadIdx.x, y = threadIdx.y;
  #pragma unroll
  for (int j = 0; j < 4; ++j)
    tile[y + j * 8][x] = in[(by * 32 + y + j * 8) * 512 + bx * 32 + x];
  __syncthreads();
  #pragma unroll
  for (int j = 0; j < 4; ++j)
    out[(bx * 32 + y + j * 8) * 1536 + by * 32 + x] = tile[x][y + j * 8];
}

__global__ __launch_bounds__(256) void k_proj(const float* __restrict__ emb0,
                                              const float* __restrict__ emb1,
                                              const float* __restrict__ Wt_ih,
                                              float* __restrict__ proj0,
                                              float* __restrict__ proj1) {
  __shared__ float a[8][NE];
  int g0 = blockIdx.x * 8;
  int tid = threadIdx.x;
  for (int i = tid; i < 8 * NE; i += 256) {
    int v = g0 + (i >> 8);
    int k = i & 255;
    a[i >> 8][k] = (v < NV0) ? emb0[v * NE + k] : emb1[(v - NV0) * NE + k];
  }
  __syncthreads();
  bool is0 = (g0 < NV0);
  int koff = is0 ? 0 : NE;
  float acc[8][6];
  #pragma unroll
  for (int v = 0; v < 8; ++v)
    #pragma unroll
    for (int j = 0; j < 6; ++j) acc[v][j] = 0.f;
  for (int k = 0; k < NE; ++k) {
    const float* wrow = Wt_ih + (size_t)(k + koff) * G3H;
    float w[6];
    #pragma unroll
    for (int j = 0; j < 6; ++j) w[j] = wrow[tid + j * 256];
    #pragma unroll
    for (int v = 0; v < 8; ++v) {
      float av = a[v][k];
      #pragma unroll
      for (int j = 0; j < 6; ++j) acc[v][j] += av * w[j];
    }
  }
  float* outp = is0 ? (proj0 + (size_t)g0 * G3H) : (proj1 + (size_t)(g0 - NV0) * G3H);
  for (int v = 0; v < 8; ++v)
    for (int j = 0; j < 6; ++j)
      outp[(size_t)v * G3H + tid + j * 256] = acc[v][j];
}

// W_hh split (rnn layout): itemrow=(hh>>5)*96+g*32+(hh&31)
__global__ void k_wsplit(const float* __restrict__ W_hh, u16* __restrict__ Wfh,
                         u16* __restrict__ Wfl) {
  int idx = blockIdx.x * blockDim.x + threadIdx.x;
  if (idx >= G3H * NH) return;
  int row = idx >> 9, k = idx & 511;
  int g = row >> 9, hh = row & 511;
  int itemrow = (hh >> 5) * 96 + g * 32 + (hh & 31);
  size_t phys = ((size_t)((itemrow >> 4) * 64 + (k >> 3))) * 128 + (itemrow & 15) * 8 + (k & 7);
  float v = W_hh[idx];
  u16 hi = bf16_hi(v);
  Wfh[phys] = hi;
  Wfl[phys] = bf16_hi(v - bf16_f(hi));
}

__global__ void k_wsplit_dec(const float* __restrict__ W, u16* __restrict__ Wh,
                             u16* __restrict__ Wl, int R) {
  int idx = blockIdx.x * blockDim.x + threadIdx.x;
  if (idx >= R * 512) return;
  int row = idx >> 9, k = idx & 511;
  size_t phys = ((size_t)(row >> 4) * 64 + (k >> 3)) * 128 + (row & 15) * 8 + (k & 7);
  float v = W[idx];
  u16 hi = bf16_hi(v);
  Wh[phys] = hi;
  Wl[phys] = bf16_hi(v - bf16_f(hi));
}

__global__ void k_levels(const int* __restrict__ cond, int* __restrict__ plv,
                         int* __restrict__ cntb) {
  __shared__ int c_lds[NT];
  __shared__ int lvl[NT + 1];
  __shared__ int cnt[NT + 1];
  int b = blockIdx.x, tid = threadIdx.x;
  for (int i = tid; i < NT; i += 256) c_lds[i] = cond[b * NT + i];
  for (int i = tid; i <= NT; i += 256) cnt[i] = 0;
  __syncthreads();
  if (tid == 0) {
    lvl[0] = 0;
    for (int t = 0; t < NT; ++t) {
      lvl[t + 1] = lvl[c_lds[t]] + 1;
      cnt[lvl[t + 1] - 1]++;
    }
  }
  __syncthreads();
  for (int t = tid; t < NT; t += 256) plv[b * NT + t] = lvl[t + 1] - 1;
  for (int p = tid; p <= NT; p += 256) cntb[p * NB + b] = cnt[p];
}

// scan + build item list (sorted by level): desc = (start<<7)|(nb<<2)|chunk
__global__ void k_scan(const int* __restrict__ cntb, int* __restrict__ level_offset,
                       int* __restrict__ startpb, int* __restrict__ items,
                       int* __restrict__ meta) {
  __shared__ int rowsum[NT + 1];
  __shared__ int itemoff[NT + 1];
  int tid = threadIdx.x;
  for (int p = tid; p <= NT; p += 1024) {
    int s = 0;
    for (int b = 0; b < NB; ++b) s += cntb[p * NB + b];
    rowsum[p] = s;
  }
  __syncthreads();
  if (tid == 0) {
    int off = 0, io = 0;
    for (int p = 0; p <= NT; ++p) {
      level_offset[p] = off;
      itemoff[p] = io;
      off += rowsum[p];
      io += ((rowsum[p] + 15) >> 4) << 2;
    }
    meta[3] = io;   // total items
    meta[4] = 0;    // queue head
  }
  __syncthreads();
  for (int p = tid; p <= NT; p += 1024) {
    int n = rowsum[p], base = level_offset[p], io = itemoff[p];
    for (int g0 = 0; g0 < n; g0 += 16) {
      int nb = n - g0; if (nb > 16) nb = 16;
      int st = base + g0;
      #pragma unroll
      for (int c = 0; c < 4; ++c) items[io++] = (st << 7) | (nb << 2) | c;
    }
  }
  __syncthreads();
  for (int p = tid; p <= NT; p += 1024) {
    int off = level_offset[p];
    for (int b = 0; b < NB; ++b) {
      startpb[p * NB + b] = off;
      off += cntb[p * NB + b];
    }
  }
}

__global__ void k_scatter(const int* __restrict__ plv, const int* __restrict__ startpb,
                          int* __restrict__ node_list) {
  __shared__ int cur[NT + 1];
  int b = blockIdx.x, tid = threadIdx.x;
  for (int p = tid; p <= NT; p += 256) cur[p] = startpb[p * NB + b];
  __syncthreads();
  if (tid == 0) {
    for (int t = 0; t < NT; ++t) {
      int p = plv[b * NT + t];
      node_list[cur[p]++] = (b << 16) | t;
    }
  }
}

// ---------------- recurrence: fence-free dataflow, persistent work queue ----------------
// State rows are packed u32 (bf16 hi | lo<<16), accessed ONLY via agent-scope
// relaxed atomics (sc0/sc1 -> coherent at L3; no L2 fences anywhere).

__global__ __launch_bounds__(512, 2) void rnn_steps(
    const int* __restrict__ items, const int* __restrict__ meta,
    const int* __restrict__ node_list, const int* __restrict__ cond,
    const int* __restrict__ tok0, const int* __restrict__ tok1,
    const u16* __restrict__ Wfh, const u16* __restrict__ Wfl,
    const float* __restrict__ proj0, const float* __restrict__ proj1,
    const float* __restrict__ b_ih, const float* __restrict__ b_hh,
    u32* __restrict__ bufp, int* done, int* qhead) {
  __shared__ unsigned char hds_h[16 * 1024];
  __shared__ unsigned char hds_l[16 * 1024];
  __shared__ int s_tb[16], s_par[16], s_k0[16], s_k1[16];
  __shared__ int s_item;
  int tid = threadIdx.x;
  int v = tid >> 6, lane = tid & 63, q = lane >> 4, m = lane & 15;
  int total = meta[3];
  for (;;) {
    __syncthreads();   // protect s_item / LDS from previous iteration
    if (tid == 0)
      s_item = __hip_atomic_fetch_add(qhead, 1, __ATOMIC_RELAXED, __HIP_MEMORY_SCOPE_AGENT);
    __syncthreads();
    int it = s_item;
    if (it >= total) break;
    int desc = items[it];
    int start = desc >> 7, nb = (desc >> 2) & 31, c = desc & 3;
    if (tid < 16) {
      int b = 0, t = -1, par = 0, q0 = 0, q1 = 0;
      if (tid < nb) {
        int pk = node_list[start + tid];
        b = pk >> 16; t = pk & 0xFFFF;
        par = cond[b * NT + t];
        q0 = tok0[b * NT + t];
        q1 = tok1[b * NT + t];
      }
      int sp = par * NB + b;
      s_tb[tid] = (t + 1) * NB + b;
      s_par[tid] = sp;
      s_k0[tid] = q0; s_k1[tid] = q1;
      // spin until parent state complete (4 chunk-WGs done)
      while (__hip_atomic_load(&done[sp], __ATOMIC_RELAXED, __HIP_MEMORY_SCOPE_AGENT) < 4)
        __builtin_amdgcn_s_sleep(2);
    }
    __syncthreads();
    asm volatile("" ::: "memory");
    // stage 16 parent states (512 packed u32 each) into split hi/lo LDS (swizzled)
    {
      int r = tid >> 5;
      int w0 = (tid & 31) * 16;
      size_t src = (size_t)s_par[r] * NH + w0;
      u32 wv[16];
      #pragma unroll
      for (int k2 = 0; k2 < 16; ++k2)
        wv[k2] = __hip_atomic_load(&bufp[src + k2], __ATOMIC_RELAXED, __HIP_MEMORY_SCOPE_AGENT);
      #pragma unroll
      for (int k2 = 0; k2 < 16; k2 += 2) {
        int w = w0 + k2;
        int a = r * 1024 + (((w >> 3) * 16) ^ ((r & 7) << 4)) + ((2 * w) & 15);
        *(u32*)(hds_h + a) = (wv[k2] & 0xFFFFu) | (wv[k2 + 1] << 16);
        *(u32*)(hds_l + a) = (wv[k2] >> 16) | (wv[k2 + 1] & 0xFFFF0000u);
      }
    }
    __syncthreads();
    // MFMA: wave v owns hh-16-block hb=c*8+v, gates 0..2; 16 nodes, K=512, 3-split
    int hb = c * 8 + v;
    int trbase = (hb >> 1) * 6 + (hb & 1);
    f32x4 a0 = {0.f, 0.f, 0.f, 0.f}, a1 = {0.f, 0.f, 0.f, 0.f}, a2 = {0.f, 0.f, 0.f, 0.f};
    const u16* wh = Wfh + (size_t)trbase * 8192;
    const u16* wl = Wfl + (size_t)trbase * 8192;
    #pragma unroll 4
    for (int s = 0; s < 16; ++s) {
      int ab = m * 1024 + (((s * 64) + (q * 16)) ^ ((m & 7) << 4));
      bf16x8 ah = *(const bf16x8*)(hds_h + ab);
      bf16x8 al = *(const bf16x8*)(hds_l + ab);
      size_t koff = (size_t)(s * 4 + q) * 128 + m * 8;
      bf16x8 bh0 = *(const bf16x8*)(wh + koff);
      bf16x8 bl0 = *(const bf16x8*)(wl + koff);
      bf16x8 bh1 = *(const bf16x8*)(wh + 16384 + koff);
      bf16x8 bl1 = *(const bf16x8*)(wl + 16384 + koff);
      bf16x8 bh2 = *(const bf16x8*)(wh + 32768 + koff);
      bf16x8 bl2 = *(const bf16x8*)(wl + 32768 + koff);
      a0 = __builtin_amdgcn_mfma_f32_16x16x32_bf16(ah, bh0, a0, 0, 0, 0);
      a0 = __builtin_amdgcn_mfma_f32_16x16x32_bf16(ah, bl0, a0, 0, 0, 0);
      a0 = __builtin_amdgcn_mfma_f32_16x16x32_bf16(al, bh0, a0, 0, 0, 0);
      a1 = __builtin_amdgcn_mfma_f32_16x16x32_bf16(ah, bh1, a1, 0, 0, 0);
      a1 = __builtin_amdgcn_mfma_f32_16x16x32_bf16(ah, bl1, a1, 0, 0, 0);
      a1 = __builtin_amdgcn_mfma_f32_16x16x32_bf16(al, bh1, a1, 0, 0, 0);
      a2 = __builtin_amdgcn_mfma_f32_16x16x32_bf16(ah, bh2, a2, 0, 0, 0);
      a2 = __builtin_amdgcn_mfma_f32_16x16x32_bf16(ah, bl2, a2, 0, 0, 0);
      a2 = __builtin_amdgcn_mfma_f32_16x16x32_bf16(al, bh2, a2, 0, 0, 0);
    }
    // in-register GRU nonlinearity; state store as packed u32 agent-atomics
    int hh = hb * 16 + m;
    float bi_r = b_ih[hh] + b_hh[hh];
    float bi_z = b_ih[NH + hh] + b_hh[NH + hh];
    float bi_n = b_ih[2 * NH + hh];
    float bh_n = b_hh[2 * NH + hh];
    #pragma unroll
    for (int i = 0; i < 4; ++i) {
      int node = q * 4 + i;
      if (node < nb) {
        const float* p0 = proj0 + (size_t)s_k0[node] * G3H;
        const float* p1 = proj1 + (size_t)s_k1[node] * G3H;
        float gr = a0[i] + p0[hh] + p1[hh] + bi_r;
        float gz = a1[i] + p0[NH + hh] + p1[NH + hh] + bi_z;
        float gin = p0[2 * NH + hh] + p1[2 * NH + hh] + bi_n;
        float ghn = a2[i] + bh_n;
        float rg = 1.f / (1.f + __expf(-gr));
        float zg = 1.f / (1.f + __expf(-gz));
        float nn = 1.f - 2.f / (1.f + __expf(2.f * (gin + rg * ghn)));
        int hofs = node * 1024 + ((hh * 2) ^ ((node & 7) << 4));
        float hp = bf16_f(*(const u16*)(hds_h + hofs)) + bf16_f(*(const u16*)(hds_l + hofs));
        float hn = (1.f - zg) * nn + zg * hp;
        __hip_atomic_store(&bufp[(size_t)s_tb[node] * NH + hh], pack_hl(hn),
                           __ATOMIC_RELAXED, __HIP_MEMORY_SCOPE_AGENT);
      }
    }
    __syncthreads();  // compiler drains vmcnt(0) before s_barrier -> stores visible at L3
    if (tid < nb)
      __hip_atomic_fetch_add(&done[s_tb[tid]], 1, __ATOMIC_RELAXED, __HIP_MEMORY_SCOPE_AGENT);
  }
}

// ---------------- decode GEMM: MFMA bf16 3-split, packed-state input ----------------

__global__ __launch_bounds__(256) void k_dec(const u32* __restrict__ bufp,
                                             const u16* __restrict__ Wh,
                                             const u16* __restrict__ Wl,
                                             const float* __restrict__ bias,
                                             float* __restrict__ out, int N) {
  __shared__ u16 Ah[64 * 128];
  __shared__ u16 Al[64 * 128];
  int tid = threadIdx.x;
  int w = tid >> 6, lane = tid & 63, q = lane >> 4, m = lane & 15;
  int n0 = blockIdx.x * 64, m0 = blockIdx.y * 64;
  f32x4 acc[4];
  #pragma unroll
  for (int n = 0; n < 4; ++n) acc[n] = (f32x4){0.f, 0.f, 0.f, 0.f};
  for (int c = 0; c < 4; ++c) {
    __syncthreads();
    #pragma unroll
    for (int r = 0; r < 8; ++r) {
      int idx = r * 256 + tid;           // 2048 16B-loads = 64 rows x 32 segs
      int row = idx >> 5, seg = idx & 31;
      int gm = m0 + row;
      size_t bufrow = (size_t)((gm & (NT - 1)) + 1) * NB + (gm >> 10);
      uint4 vv = *(const uint4*)(bufp + bufrow * NH + c * 128 + seg * 4);
      int a = row * 256 + (((seg >> 1) * 16) ^ ((row & 7) << 4)) + (seg & 1) * 8;
      uint2 hp, lp;
      hp.x = (vv.x & 0xFFFFu) | (vv.y << 16);
      hp.y = (vv.z & 0xFFFFu) | (vv.w << 16);
      lp.x = (vv.x >> 16) | (vv.y & 0xFFFF0000u);
      lp.y = (vv.z >> 16) | (vv.w & 0xFFFF0000u);
      *(uint2*)((unsigned char*)Ah + a) = hp;
      *(uint2*)((unsigned char*)Al + a) = lp;
    }
    __syncthreads();
    #pragma unroll
    for (int s = 0; s < 4; ++s) {
      int arow = w * 16 + m;
      int aoff = arow * 256 + (((s * 64) + (q * 16)) ^ ((arow & 7) << 4));
      bf16x8 ah = *(const bf16x8*)((unsigned char*)Ah + aoff);
      bf16x8 al = *(const bf16x8*)((unsigned char*)Al + aoff);
      #pragma unroll
      for (int n = 0; n < 4; ++n) {
        size_t b = ((size_t)(n0 / 16 + n) * 64 + (c * 16 + s * 4 + q)) * 128 + m * 8;
        bf16x8 bh = *(const bf16x8*)(Wh + b);
        bf16x8 bl = *(const bf16x8*)(Wl + b);
        acc[n] = __builtin_amdgcn_mfma_f32_16x16x32_bf16(ah, bh, acc[n], 0, 0, 0);
        acc[n] = __builtin_amdgcn_mfma_f32_16x16x32_bf16(ah, bl, acc[n], 0, 0, 0);
        acc[n] = __builtin_amdgcn_mfma_f32_16x16x32_bf16(al, bh, acc[n], 0, 0, 0);
      }
    }
  }
  #pragma unroll
  for (int n = 0; n < 4; ++n) {
    int col = n0 + n * 16 + m;
    float bv = bias[col];
    #pragma unroll
    for (int i = 0; i < 4; ++i) {
      int mrow = m0 + w * 16 + q * 4 + i;
      out[(size_t)mrow * N + col] = acc[n][i] + bv;
    }
  }
}

__global__ void k_tail(const u32* __restrict__ bufp, float* __restrict__ out) {
  int i = blockIdx.x * blockDim.x + threadIdx.x;
  if (i < NB * NH) out[i] = unpack_hl(bufp[(size_t)NT * NB * NH + i]);
}

// ---------------- launch ----------------

extern "C" void kernel_launch(void* const* d_in, const int* in_sizes, int n_in,
                              void* d_out, int out_size, void* d_ws, size_t ws_size,
                              hipStream_t stream) {
  const int*   tokens0    = (const int*)d_in[0];
  const int*   tokens1    = (const int*)d_in[1];
  const int*   conditions = (const int*)d_in[2];
  const float* hidden     = (const float*)d_in[3];
  const float* emb0       = (const float*)d_in[4];
  const float* emb1       = (const float*)d_in[5];
  const float* W_ih       = (const float*)d_in[6];
  const float* W_hh       = (const float*)d_in[7];
  const float* b_ih       = (const float*)d_in[8];
  const float* b_hh       = (const float*)d_in[9];
  const float* dec0_W     = (const float*)d_in[10];
  const float* dec0_b     = (const float*)d_in[11];
  const float* dec1_W     = (const float*)d_in[12];
  const float* dec1_b     = (const float*)d_in[13];

  char* wsb = (char*)d_ws;
  float* proj0 = (float*)wsb;                      // 12,582,912 B
  float* proj1 = (float*)(wsb + 12582912);         //  3,145,728 B
  float* Wt_ih = (float*)(wsb + 15728640);         //  3,145,728 B (reused below)
  // done/items overlap Wt_ih's region: used only AFTER k_proj finishes (stream order)
  int*   done  = (int*)(wsb + 15728640);           // 32800 ints = 131,200 B
  int*   items = (int*)(wsb + 15859840);           // 16384 ints =  65,536 B
  u32*   bufp  = (u32*)(wsb + 18874368);           // 1025*32*512 u32 = 67,174,400 B
  u16*   Wfh   = (u16*)(wsb + 86048768);           //  1,572,864 B
  u16*   Wfl   = (u16*)(wsb + 87621632);           //  1,572,864 B
  u16*   d0Wh  = (u16*)(wsb + 89194496);           //  2,097,152 B
  u16*   d0Wl  = (u16*)(wsb + 91291648);           //  2,097,152 B
  u16*   d1Wh  = (u16*)(wsb + 93388800);           //    524,288 B
  u16*   d1Wl  = (u16*)(wsb + 93913088);           //    524,288 B
  int*   iws   = (int*)(wsb + 94437376);
  int* plv          = iws;                 // 32768
  int* cntb         = iws + 32768;         // 32800
  int* level_offset = iws + 65568;         // 1026
  int* startpb      = iws + 66594;         // 32800
  int* meta         = iws + 99394;         // 8  ([3]=total items, [4]=qhead)
  int* node_list    = iws + 99402;         // 32768

  float* out0 = (float*)d_out;
  float* out1 = out0 + (size_t)NB * NT * NV0;
  float* outT = out1 + (size_t)NB * NT * NV1;

  // Wt_ih produced+consumed first; then its region is reused for done/items.
  k_transpose<<<dim3(16, 48), dim3(32, 8), 0, stream>>>(W_ih, Wt_ih);
  k_proj<<<320, 256, 0, stream>>>(emb0, emb1, Wt_ih, proj0, proj1);
  k_init<<<130, 256, 0, stream>>>(hidden, bufp, done);
  k_wsplit<<<3072, 256, 0, stream>>>(W_hh, Wfh, Wfl);
  k_wsplit_dec<<<4096, 256, 0, stream>>>(dec0_W, d0Wh, d0Wl, NV0);
  k_wsplit_dec<<<1024, 256, 0, stream>>>(dec1_W, d1Wh, d1Wl, NV1);
  k_levels<<<32, 256, 0, stream>>>(conditions, plv, cntb);
  k_scan<<<1, 1024, 0, stream>>>(cntb, level_offset, startpb, items, meta);
  k_scatter<<<32, 256, 0, stream>>>(plv, startpb, node_list);

  rnn_steps<<<512, 512, 0, stream>>>(items, meta, node_list, conditions, tokens0, tokens1,
                                     Wfh, Wfl, proj0, proj1, b_ih, b_hh,
                                     bufp, done, meta + 4);

  k_dec<<<dim3(NV0 / 64, (NB * NT) / 64), 256, 0, stream>>>(bufp, d0Wh, d0Wl, dec0_b, out0, NV0);
  k_dec<<<dim3(NV1 / 64, (NB * NT) / 64), 256, 0, stream>>>(bufp, d1Wh, d1Wl, dec1_b, out1, NV1);
  k_tail<<<64, 256, 0, stream>>>(bufp, outT);
}